// Round 6
// baseline (328.097 us; speedup 1.0000x reference)
//
#include <hip/hip_runtime.h>
#include <hip/hip_cooperative_groups.h>
#include <math.h>

namespace cg = cooperative_groups;

#define BB 8
#define CC 64
#define NN 4096
#define CI 8
#define GAMMA 0.1f
// exp(s/sqrt(8)) = exp2(s * log2(e)/sqrt(8)); folded into k in phase 1.
#define SCALE (1.44269504088896f * 0.35355339059327f)
#define MT 2
#define NCHUNK 128

typedef float v2f __attribute__((ext_vector_type(2)));
typedef float v4f __attribute__((ext_vector_type(4)));

__device__ __forceinline__ float fast_exp2(float x) {
    return __builtin_amdgcn_exp2f(x);
}

// ONE cooperative kernel, three phases separated by grid.sync().
// R3/R4/R5 evidence: the ~68us non-att tail survived three different
// qkv/out structures -> it's dispatch/serialization overhead, not kernel
// work. Single dispatch removes it (or proves it harness-fixed).
// Phase bodies are math-identical to the proven R4 kernels.
__global__ __launch_bounds__(256, 8) void fused_kernel(
        const float* __restrict__ x,
        const float* __restrict__ Wq, const float* __restrict__ Wk,
        const float* __restrict__ Wv, const float* __restrict__ Wout,
        float* __restrict__ qv, float* __restrict__ kb,
        float* __restrict__ attab, float* __restrict__ out) {
    __shared__ float smem[2176];   // 8.7 KB: phase1 = sw(1536)+sqv(640); phase2 = 2048
    cg::grid_group grid = cg::this_grid();
    const int t = threadIdx.x;

    // ================= phase 1: qkv + zero attab =================
    {
        // zero attab (visible to phase 2 via grid.sync)
        for (int idx = blockIdx.x * 256 + t; idx < BB * 9 * NN; idx += gridDim.x * 256)
            attab[idx] = 0.f;

        float* sw  = smem;          // Wq | Wk*SCALE | Wv (512 each)
        float* sqv = smem + 1536;   // [32][20] padded
        for (int idx = t; idx < CI * CC; idx += 256) {
            sw[idx]        = Wq[idx];
            sw[512 + idx]  = Wk[idx] * SCALE;
            sw[1024 + idx] = Wv[idx];
        }
        __syncthreads();
        const int i  = t >> 5;      // 0..7
        const int nl = t & 31;      // 0..31
        for (int tile = blockIdx.x; tile < BB * (NN / 32); tile += gridDim.x) {
            const int b  = tile >> 7;           // 128 tiles per b
            const int n0 = (tile & 127) * 32;
            const int n  = n0 + nl;
            const float* xp = x + ((size_t)b * CC) * NN + n;
            const v4f* wq4 = (const v4f*)(sw + i * CC);
            const v4f* wk4 = (const v4f*)(sw + 512 + i * CC);
            const v4f* wv4 = (const v4f*)(sw + 1024 + i * CC);
            float qa = 0.f, ka = 0.f, va = 0.f;
#pragma unroll 4
            for (int c4 = 0; c4 < CC / 4; ++c4) {
                v4f wq = wq4[c4], wk = wk4[c4], wv = wv4[c4];   // LDS broadcast
                float x0 = xp[(size_t)(c4 * 4 + 0) * NN];
                float x1 = xp[(size_t)(c4 * 4 + 1) * NN];
                float x2 = xp[(size_t)(c4 * 4 + 2) * NN];
                float x3 = xp[(size_t)(c4 * 4 + 3) * NN];
                qa = fmaf(wq.x, x0, qa); ka = fmaf(wk.x, x0, ka); va = fmaf(wv.x, x0, va);
                qa = fmaf(wq.y, x1, qa); ka = fmaf(wk.y, x1, ka); va = fmaf(wv.y, x1, va);
                qa = fmaf(wq.z, x2, qa); ka = fmaf(wk.z, x2, ka); va = fmaf(wv.z, x2, va);
                qa = fmaf(wq.w, x3, qa); ka = fmaf(wk.w, x3, ka); va = fmaf(wv.w, x3, va);
            }
            kb[((size_t)b * CI + i) * NN + n] = ka;   // coalesced
            sqv[nl * 20 + i]     = qa;
            sqv[nl * 20 + 8 + i] = va;
            __syncthreads();
            if (t < 128) {   // 512 words -> 128 float4, coalesced 2KB store
                int w = t * 4;
                int nn2 = w >> 4, p = w & 15;
                v4f val = *(const v4f*)(sqv + nn2 * 20 + p);
                *(v4f*)(qv + ((size_t)b * NN + n0 + nn2) * 16 + p) = val;
            }
            __syncthreads();   // protect sqv for next tile
        }
    }
    grid.sync();

    // ================= phase 2: attention core =================
    // |scores| < ~2 -> exp without max-subtraction is safe (shift-invariant).
    // attab[b][9][N]: rows 0..7 = sum_n e*v_i, row 8 = sum_n e. (R4 structure.)
    {
        float* sq = smem;   // 2048 floats
        for (int bid = blockIdx.x; bid < 2048; bid += gridDim.x) {
            const int b  = bid >> 8;
            const int nc = (bid >> 3) & 31;
            const int mt = bid & 7;
            const int n0 = nc * NCHUNK;
            const int m0 = mt * (256 * MT);

            __syncthreads();   // smem reuse guard across bid iterations
            const float4* src = (const float4*)(qv + ((size_t)b * NN + n0) * 16);
            float4* dst = (float4*)sq;
            for (int ii = t; ii < NCHUNK * 4; ii += 256) dst[ii] = src[ii];
            __syncthreads();

            v2f kr[MT][4];
            int mm[MT];
#pragma unroll
            for (int j = 0; j < MT; ++j) {
                int m = m0 + t + 256 * j;
                mm[j] = m;
#pragma unroll
                for (int i = 0; i < 4; ++i) {
                    float k0 = kb[((size_t)b * CI + 2 * i) * NN + m];
                    float k1 = kb[((size_t)b * CI + 2 * i + 1) * NN + m];
                    kr[j][i] = (v2f){k0, k1};
                }
            }
            v2f acc[MT][4];
            float es[MT];
#pragma unroll
            for (int j = 0; j < MT; ++j) {
                es[j] = 0.f;
#pragma unroll
                for (int i = 0; i < 4; ++i) acc[j][i] = (v2f){0.f, 0.f};
            }

            for (int n = 0; n < NCHUNK; ++n) {
                const float* p = sq + n * 16;   // same addr all lanes: broadcast
                v4f qa = *(const v4f*)(p);
                v4f qb = *(const v4f*)(p + 4);
                v4f va = *(const v4f*)(p + 8);
                v4f vb = *(const v4f*)(p + 12);
                v2f q01 = {qa.x, qa.y}, q23 = {qa.z, qa.w};
                v2f q45 = {qb.x, qb.y}, q67 = {qb.z, qb.w};
                v2f v01 = {va.x, va.y}, v23 = {va.z, va.w};
                v2f v45 = {vb.x, vb.y}, v67 = {vb.z, vb.w};
#pragma unroll
                for (int j = 0; j < MT; ++j) {
                    v2f s2 = q01 * kr[j][0];
                    s2 = __builtin_elementwise_fma(q23, kr[j][1], s2);
                    s2 = __builtin_elementwise_fma(q45, kr[j][2], s2);
                    s2 = __builtin_elementwise_fma(q67, kr[j][3], s2);
                    float e = fast_exp2(s2.x + s2.y);
                    es[j] += e;
                    v2f e2 = {e, e};
                    acc[j][0] = __builtin_elementwise_fma(e2, v01, acc[j][0]);
                    acc[j][1] = __builtin_elementwise_fma(e2, v23, acc[j][1]);
                    acc[j][2] = __builtin_elementwise_fma(e2, v45, acc[j][2]);
                    acc[j][3] = __builtin_elementwise_fma(e2, v67, acc[j][3]);
                }
            }
#pragma unroll
            for (int j = 0; j < MT; ++j) {
                float* ap = attab + (size_t)b * 9 * NN + mm[j];
#pragma unroll
                for (int i = 0; i < 4; ++i) {
                    atomicAdd(ap + (size_t)(2 * i) * NN, acc[j][i].x);
                    atomicAdd(ap + (size_t)(2 * i + 1) * NN, acc[j][i].y);
                }
                atomicAdd(ap + (size_t)8 * NN, es[j]);
            }
        }
    }
    grid.sync();

    // ================= phase 3: out projection + residual =================
    // One float4 (4 m) per thread; c is block-uniform within each 256-quad
    // chunk (1024 quads per (b,c)) -> Wout via scalar loads.
    for (int q = blockIdx.x * 256 + t; q < BB * CC * (NN / 4); q += gridDim.x * 256) {
        const int m4   = q & (NN / 4 - 1);
        const int rest = q >> 10;
        const int c = rest & (CC - 1);
        const int b = rest >> 6;
        const int m = m4 * 4;
        const float* ap = attab + (size_t)b * 9 * NN + m;
        v4f sum = *(const v4f*)(ap + (size_t)8 * NN);
        v4f s = {0.f, 0.f, 0.f, 0.f};
#pragma unroll
        for (int i = 0; i < CI; ++i) {
            float w = Wout[c * CI + i];
            v4f a = *(const v4f*)(ap + (size_t)i * NN);
            s.x = fmaf(w, a.x, s.x);
            s.y = fmaf(w, a.y, s.y);
            s.z = fmaf(w, a.z, s.z);
            s.w = fmaf(w, a.w, s.w);
        }
        size_t o = ((size_t)b * CC + c) * NN + m;
        v4f xv = *(const v4f*)(x + o);
        v4f r;
        r.x = xv.x + GAMMA * (s.x / sum.x);
        r.y = xv.y + GAMMA * (s.y / sum.y);
        r.z = xv.z + GAMMA * (s.z / sum.z);
        r.w = xv.w + GAMMA * (s.w / sum.w);
        *(v4f*)(out + o) = r;
    }
}

extern "C" void kernel_launch(void* const* d_in, const int* in_sizes, int n_in,
                              void* d_out, int out_size, void* d_ws, size_t ws_size,
                              hipStream_t stream) {
    const float* x    = (const float*)d_in[0];
    const float* Wq   = (const float*)d_in[1];
    const float* Wk   = (const float*)d_in[2];
    const float* Wv   = (const float*)d_in[3];
    const float* Wout = (const float*)d_in[4];
    float* out = (float*)d_out;
    float* ws  = (float*)d_ws;

    // ws layout (floats): qv [B][N][16] | kb [B][8][N] | attab [B][9][N]
    float* qv    = ws;
    float* kb    = ws + (size_t)BB * NN * 16;
    float* attab = kb + (size_t)BB * CI * NN;

    // Clamp grid to co-resident capacity (cooperative launch requirement).
    int occ = 8;
    hipOccupancyMaxActiveBlocksPerMultiprocessor(&occ, fused_kernel, 256, 0);
    if (occ < 1) occ = 1;
    int grid = occ * 256;            // 256 CUs on MI355X
    if (grid > 2048) grid = 2048;

    void* args[] = {(void*)&x, (void*)&Wq, (void*)&Wk, (void*)&Wv, (void*)&Wout,
                    (void*)&qv, (void*)&kb, (void*)&attab, (void*)&out};
    hipLaunchCooperativeKernel((const void*)fused_kernel, dim3(grid), dim3(256),
                               args, 0, stream);
}

// Round 7
// 114.376 us; speedup vs baseline: 2.8686x; 2.8686x over previous
//
#include <hip/hip_runtime.h>
#include <math.h>

#define BB 8
#define CC 64
#define NN 4096
#define CI 8
#define GAMMA 0.1f
// exp(s/sqrt(8)) = exp2(s * log2(e)/sqrt(8)); folded into k in qkv.
#define SCALE (1.44269504088896f * 0.35355339059327f)
#define NSPLIT 4

typedef float v4f __attribute__((ext_vector_type(4)));
typedef __bf16 bf16x8 __attribute__((ext_vector_type(8)));
typedef __bf16 bf16x4 __attribute__((ext_vector_type(4)));
typedef __bf16 bf16x2 __attribute__((ext_vector_type(2)));

__device__ __forceinline__ float fast_exp2(float x) {
    return __builtin_amdgcn_exp2f(x);
}

// Grid (NN/32, BB); block 256 = 8 i-groups x 32 n (R4-proven structure).
// Outputs (bf16 for MFMA att):
//   qbh[b][n][8]  : q fragment rows (16B per n, contiguous)  [A-frag for S]
//   kbh[b][m][8]  : k*SCALE fragment rows (16B per m)        [B-frag for S]
//   vbh[b][i][N]  : v rows, contiguous in n                  [A-frag for PV]
// Also zeros attab[b][9][N] (fp32 accumulators for att phase).
__global__ __launch_bounds__(256) void qkv_kernel(
        const float* __restrict__ x,
        const float* __restrict__ Wq, const float* __restrict__ Wk,
        const float* __restrict__ Wv,
        __bf16* __restrict__ qbh, __bf16* __restrict__ kbh,
        __bf16* __restrict__ vbh, float* __restrict__ attab) {
    __shared__ float sw[3 * CI * CC];     // 6 KB: Wq | Wk*SCALE | Wv
    __shared__ unsigned short sq[32 * 8]; // bf16 tile [n_local][i]
    __shared__ unsigned short sk[32 * 8];
    const int t = threadIdx.x;
    const int i  = t >> 5;          // 0..7
    const int nl = t & 31;          // 0..31
    const int b  = blockIdx.y;
    const int n0 = blockIdx.x * 32;

    for (int idx = t; idx < CI * CC; idx += 256) {
        sw[idx]                = Wq[idx];
        sw[CI * CC + idx]      = Wk[idx] * SCALE;
        sw[2 * CI * CC + idx]  = Wv[idx];
    }
    // zero attab: 294912 elems over 262144 threads (<=2 stores each)
    int lin = (blockIdx.y * (NN / 32) + blockIdx.x) * 256 + t;
    for (int idx = lin; idx < BB * 9 * NN; idx += BB * NN * CI) attab[idx] = 0.f;
    __syncthreads();

    const int n = n0 + nl;
    const float* xp = x + ((size_t)b * CC) * NN + n;
    const v4f* wq4 = (const v4f*)(sw + i * CC);
    const v4f* wk4 = (const v4f*)(sw + CI * CC + i * CC);
    const v4f* wv4 = (const v4f*)(sw + 2 * CI * CC + i * CC);
    float qa = 0.f, ka = 0.f, va = 0.f;
#pragma unroll 4
    for (int c4 = 0; c4 < CC / 4; ++c4) {
        v4f wq = wq4[c4], wk = wk4[c4], wv = wv4[c4];   // LDS broadcast b128
        float x0 = xp[(size_t)(c4 * 4 + 0) * NN];
        float x1 = xp[(size_t)(c4 * 4 + 1) * NN];
        float x2 = xp[(size_t)(c4 * 4 + 2) * NN];
        float x3 = xp[(size_t)(c4 * 4 + 3) * NN];
        qa = fmaf(wq.x, x0, qa); ka = fmaf(wk.x, x0, ka); va = fmaf(wv.x, x0, va);
        qa = fmaf(wq.y, x1, qa); ka = fmaf(wk.y, x1, ka); va = fmaf(wv.y, x1, va);
        qa = fmaf(wq.z, x2, qa); ka = fmaf(wk.z, x2, ka); va = fmaf(wv.z, x2, va);
        qa = fmaf(wq.w, x3, qa); ka = fmaf(wk.w, x3, ka); va = fmaf(wv.w, x3, va);
    }
    // v: coalesced bf16 store (64B per i-group)
    __bf16 vb = (__bf16)va;
    vbh[((size_t)b * CI + i) * NN + n] = vb;
    // q,k: assemble [n][8] tiles in LDS, then 16B-coalesced copy out
    __bf16 qb = (__bf16)qa, kb2 = (__bf16)ka;
    sq[nl * 8 + i] = *(unsigned short*)&qb;
    sk[nl * 8 + i] = *(unsigned short*)&kb2;
    __syncthreads();
    if (t < 32) {
        *(uint4*)(qbh + ((size_t)b * NN + n0 + t) * 8) = *(const uint4*)(sq + t * 8);
        *(uint4*)(kbh + ((size_t)b * NN + n0 + t) * 8) = *(const uint4*)(sk + t * 8);
    }
}

// MFMA attention core. |scores| < ~2 -> exp without max-subtraction is safe
// (softmax shift-invariant): att[n,m] = e(s_nm)/sum_n e(s_nm).
// Per wave: 16-m tile, loop n in chunks of 32 over this block's n-range.
//   S = Q^T K tile via 2x mfma_f32_16x16x32_bf16 (A=Q rows=n, B=K cols=m;
//       only k<8 of K=32 used, rest zero).
//   e = exp2(S) -> bf16 -> per-wave LDS transpose (rows padded to 72B) ->
//       B-frag (k=n within chunk, col=m).
//   PV: A = [v0..v7; ones; 0...] (ones row gives the denominator for free,
//       rows built from constants, not memory) -> accO += A*E.
// Epilogue: 9 fp32 atomicAdd rows into attab[b][9][N] per wave.
// Grid (64 m-blocks, NSPLIT, BB) = 2048 blocks x 4 waves.
__global__ __launch_bounds__(256) void att_kernel(
        const __bf16* __restrict__ qbh, const __bf16* __restrict__ kbh,
        const __bf16* __restrict__ vbh, float* __restrict__ attab) {
    __shared__ unsigned short eld[4][16 * 36];  // per-wave transpose buf (72B rows)
    const int t = threadIdx.x;
    const int w    = t >> 6;
    const int l    = t & 63;
    const int quad = l >> 4;
    const int lm   = l & 15;
    const int b  = blockIdx.z;
    const int m0 = blockIdx.x * 64 + w * 16;
    const int nbase = blockIdx.y * (NN / NSPLIT);

    bf16x8 zero8, ones8;
#pragma unroll
    for (int z = 0; z < 8; ++z) { zero8[z] = (__bf16)0.0f; ones8[z] = (__bf16)1.0f; }

    // K fragment: constant across the n loop. B[k=j (ci), col=lm] for quad 0.
    bf16x8 kfrag = zero8;
    if (quad == 0)
        kfrag = *(const bf16x8*)(kbh + ((size_t)b * NN + m0 + lm) * 8);

    // V fragment row source: A[row=lm][k=n]; rows 8=ones, >8=zero.
    const __bf16* vrow = vbh + ((size_t)b * CI + (lm & 7)) * NN;  // valid only lm<8

    v4f accO = {0.f, 0.f, 0.f, 0.f};
    unsigned short* ew = &eld[w][lm * 36];

    for (int ch = 0; ch < (NN / NSPLIT) / 32; ++ch) {
        const int nc = nbase + ch * 32;
        // Q fragments (A for S): row n = nc + lm (+16), k = ci for quad 0.
        bf16x8 q0 = zero8, q1 = zero8;
        if (quad == 0) {
            q0 = *(const bf16x8*)(qbh + ((size_t)b * NN + nc + lm) * 8);
            q1 = *(const bf16x8*)(qbh + ((size_t)b * NN + nc + 16 + lm) * 8);
        }
        // V fragment for this chunk: A[row=lm][k=quad*8+j] -> vbh[lm][nc+quad*8+j]
        bf16x8 vfrag;
        if (lm < 8)      vfrag = *(const bf16x8*)(vrow + nc + quad * 8);
        else if (lm == 8) vfrag = ones8;
        else              vfrag = zero8;

        v4f s0 = __builtin_amdgcn_mfma_f32_16x16x32_bf16(q0, kfrag, (v4f){0.f,0.f,0.f,0.f}, 0, 0, 0);
        v4f s1 = __builtin_amdgcn_mfma_f32_16x16x32_bf16(q1, kfrag, (v4f){0.f,0.f,0.f,0.f}, 0, 0, 0);

        // e = exp2(s); pack pairs; write transposed: eld[m=lm][n = quad*4+r (+16)]
        bf16x2 p;
        p[0] = (__bf16)fast_exp2(s0.x); p[1] = (__bf16)fast_exp2(s0.y);
        *(bf16x2*)(ew + quad * 4 + 0)  = p;
        p[0] = (__bf16)fast_exp2(s0.z); p[1] = (__bf16)fast_exp2(s0.w);
        *(bf16x2*)(ew + quad * 4 + 2)  = p;
        p[0] = (__bf16)fast_exp2(s1.x); p[1] = (__bf16)fast_exp2(s1.y);
        *(bf16x2*)(ew + 16 + quad * 4 + 0) = p;
        p[0] = (__bf16)fast_exp2(s1.z); p[1] = (__bf16)fast_exp2(s1.w);
        *(bf16x2*)(ew + 16 + quad * 4 + 2) = p;

        // read back as B-frag: B[k=quad*8+j][col=lm] = eld[lm][quad*8+j]
        const unsigned short* er = ew + quad * 8;
        bf16x4 e_lo = *(const bf16x4*)(er);       // 8B (72 and 16 both /8)
        bf16x4 e_hi = *(const bf16x4*)(er + 4);
        bf16x8 efrag;
#pragma unroll
        for (int z = 0; z < 4; ++z) { efrag[z] = e_lo[z]; efrag[4 + z] = e_hi[z]; }

        accO = __builtin_amdgcn_mfma_f32_16x16x32_bf16(vfrag, efrag, accO, 0, 0, 0);
    }

    // Epilogue: D[row=quad*4+r][col=lm]; rows 0..7 = sum e*v_i, row 8 = sum e.
    float* ap = attab + (size_t)b * 9 * NN + m0 + lm;
    float av[4] = {accO.x, accO.y, accO.z, accO.w};
#pragma unroll
    for (int r = 0; r < 4; ++r) {
        int i = quad * 4 + r;
        if (i < 9) atomicAdd(ap + (size_t)i * NN, av[r]);
    }
}

// Grid (NN/1024, CC, BB); block 256. Thread (b, c, m0): 4 m-columns via float4.
__global__ __launch_bounds__(256) void out_kernel(
        const float* __restrict__ x, const float* __restrict__ Wout,
        const float* __restrict__ attab, float* __restrict__ out) {
    const int t = threadIdx.x;
    const int c = blockIdx.y;
    const int b = blockIdx.z;
    const int m = (blockIdx.x * 256 + t) * 4;
    const float* ap = attab + (size_t)b * 9 * NN + m;
    v4f sum = *(const v4f*)(ap + (size_t)8 * NN);
    v4f s = {0.f, 0.f, 0.f, 0.f};
#pragma unroll
    for (int i = 0; i < CI; ++i) {
        float wgt = Wout[c * CI + i];               // uniform -> s_load
        v4f a = *(const v4f*)(ap + (size_t)i * NN);
        s.x = fmaf(wgt, a.x, s.x);
        s.y = fmaf(wgt, a.y, s.y);
        s.z = fmaf(wgt, a.z, s.z);
        s.w = fmaf(wgt, a.w, s.w);
    }
    size_t o = ((size_t)b * CC + c) * NN + m;
    v4f xv = *(const v4f*)(x + o);
    v4f r;
    r.x = xv.x + GAMMA * (s.x / sum.x);
    r.y = xv.y + GAMMA * (s.y / sum.y);
    r.z = xv.z + GAMMA * (s.z / sum.z);
    r.w = xv.w + GAMMA * (s.w / sum.w);
    *(v4f*)(out + o) = r;
}

extern "C" void kernel_launch(void* const* d_in, const int* in_sizes, int n_in,
                              void* d_out, int out_size, void* d_ws, size_t ws_size,
                              hipStream_t stream) {
    const float* x    = (const float*)d_in[0];
    const float* Wq   = (const float*)d_in[1];
    const float* Wk   = (const float*)d_in[2];
    const float* Wv   = (const float*)d_in[3];
    const float* Wout = (const float*)d_in[4];
    float* out = (float*)d_out;

    // ws layout: qbh [B][N][8] bf16 | kbh [B][N][8] bf16 | vbh [B][8][N] bf16 |
    //            attab [B][9][N] fp32   (~2.7 MB total)
    __bf16* qbh = (__bf16*)d_ws;
    __bf16* kbh = qbh + (size_t)BB * NN * 8;
    __bf16* vbh = kbh + (size_t)BB * NN * 8;
    float* attab = (float*)(vbh + (size_t)BB * NN * 8);

    qkv_kernel<<<dim3(NN / 32, BB), 256, 0, stream>>>(x, Wq, Wk, Wv, qbh, kbh, vbh, attab);
    att_kernel<<<dim3(NN / 64, NSPLIT, BB), 256, 0, stream>>>(qbh, kbh, vbh, attab);
    out_kernel<<<dim3(NN / 1024, CC, BB), 256, 0, stream>>>(x, Wout, attab, out);
}